// Round 9
// baseline (4794.125 us; speedup 1.0000x reference)
//
#include <hip/hip_runtime.h>

#define T_STEPS 512
#define BATCH   64
#define DIMS    256
#define NDIR    2

typedef short bf16x8 __attribute__((ext_vector_type(8)));
typedef float f32x4  __attribute__((ext_vector_type(4)));
typedef unsigned int u32x4 __attribute__((ext_vector_type(4)));

__device__ __forceinline__ unsigned short f2bf(float f) {
  union { float f; unsigned int u; } v; v.f = f;
  unsigned int b = v.u;
  return (unsigned short)((b + 0x7FFFu + ((b >> 16) & 1u)) >> 16);
}
__device__ __forceinline__ float bf2f(unsigned short s) {
  union { unsigned int u; float f; } v; v.u = ((unsigned int)s) << 16; return v.f;
}
__device__ __forceinline__ float sigm(float x) {
  return __builtin_amdgcn_rcpf(1.0f + __builtin_amdgcn_exp2f(-1.44269504f * x));
}
__device__ __forceinline__ float tanh_(float x) {
  return 1.0f - 2.0f * __builtin_amdgcn_rcpf(1.0f + __builtin_amdgcn_exp2f(2.88539008f * x));
}
__device__ __forceinline__ f32x4 bcast4(float s) {
  f32x4 v; v[0] = s; v[1] = s; v[2] = s; v[3] = s; return v;
}

// ---- prep: W [512][1024] f32 -> WT [2][1024 cols][512 k] bf16 (transposed) ----
__global__ void prep_w(const float* __restrict__ Wf, const float* __restrict__ Wb,
                       unsigned short* __restrict__ WT) {
  int d = blockIdx.x >> 10, col = blockIdx.x & 1023;
  const float* W = d ? Wb : Wf;
  int k = threadIdx.x;
  WT[((size_t)(d * 1024 + col)) * 512 + k] = f2bf(W[(size_t)k * 1024 + col]);
}

// ---- Gx = x_dir @ W_x + bias, stored bf16 [2][64 b][512 t][1024 gc] ----
// Backward direction reads x time-reversed per batch (t < L ? L-1-t : t).
// One block: 128 M-rows ((b,t) pairs) x 128 N-cols. A staged in LDS as bf16
// (XOR-swizzled); B fragments read directly from WT (L2-resident, 64KB/tile).
__global__ __launch_bounds__(512, 1) void gx_gemm(
    const float* __restrict__ x, const int* __restrict__ length,
    const unsigned short* __restrict__ WT,
    const float* __restrict__ bias_f, const float* __restrict__ bias_b,
    unsigned short* __restrict__ Gx)
{
  __shared__ unsigned char Alds[65536];   // [128 rows][256 k] bf16, swizzled
  const int bid = blockIdx.x;
  const int d = bid >> 11, mt = (bid >> 3) & 255, nt = bid & 7;
  const int tid = threadIdx.x;
  const float* bias = d ? bias_b : bias_f;

  // stage A: thread = (row r, quarter q) loads 64 f32, converts, writes 8x16B
  {
    const int r = tid >> 2, q = tid & 3;
    const int m = mt * 128 + r;
    const int b = m >> 9, t = m & 511;
    const int L = length[b];
    const int tx = (d == 0) ? t : ((t < L) ? (L - 1 - t) : t);
    const float* xp = x + ((size_t)b * 512 + tx) * 256 + q * 64;
    #pragma unroll
    for (int i = 0; i < 8; ++i) {
      const float4 v0 = *reinterpret_cast<const float4*>(xp + i * 8);
      const float4 v1 = *reinterpret_cast<const float4*>(xp + i * 8 + 4);
      union { bf16x8 v; unsigned short s[8]; } u;
      u.s[0] = f2bf(v0.x); u.s[1] = f2bf(v0.y); u.s[2] = f2bf(v0.z); u.s[3] = f2bf(v0.w);
      u.s[4] = f2bf(v1.x); u.s[5] = f2bf(v1.y); u.s[6] = f2bf(v1.z); u.s[7] = f2bf(v1.w);
      const int byte = (r * 512 + (q * 64 + i * 8) * 2) ^ ((r & 7) << 4);
      *reinterpret_cast<bf16x8*>(&Alds[byte]) = u.v;
    }
  }
  __syncthreads();

  const int lane = tid & 63, wv = tid >> 6;      // 8 waves, wave = 16 M-rows
  const int lhi = lane >> 4, llo = lane & 15;

  f32x4 acc[8];
  #pragma unroll
  for (int tc = 0; tc < 8; ++tc) acc[tc] = bcast4(bias[nt * 128 + tc * 16 + llo]);

  #pragma unroll
  for (int kf = 0; kf < 8; ++kf) {
    const int row = 16 * wv + llo;
    const int abyte = (row * 512 + (kf * 32 + lhi * 8) * 2) ^ ((row & 7) << 4);
    const bf16x8 af = *reinterpret_cast<const bf16x8*>(&Alds[abyte]);
    #pragma unroll
    for (int tc = 0; tc < 8; ++tc) {
      const unsigned short* bp =
          WT + ((size_t)(d * 1024 + nt * 128 + tc * 16 + llo)) * 512 + kf * 32 + lhi * 8;
      const bf16x8 bf = *reinterpret_cast<const bf16x8*>(bp);
      acc[tc] = __builtin_amdgcn_mfma_f32_16x16x32_bf16(af, bf, acc[tc], 0, 0, 0);
    }
  }

  #pragma unroll
  for (int tc = 0; tc < 8; ++tc) {
    #pragma unroll
    for (int j = 0; j < 4; ++j) {
      const int m = mt * 128 + 16 * wv + lhi * 4 + j;
      Gx[((size_t)(d * 32768 + m)) * 1024 + nt * 128 + tc * 16 + llo] = f2bf(acc[tc][j]);
    }
  }
}

// ---- recurrence, ZERO cross-block sync ----
// 8 blocks = 2 dirs x 4 batch-quarters; 512 threads (8 waves). Each block:
// 16 batches, full 256 h-dims. W_h register-resident (256 VGPR/lane, pinned).
// h exchanged through LDS (XOR-swizzled) with ONE __syncthreads per step.
// Gates = Gx[t] (precomputed, prefetched) + h @ W_h.
__global__ __launch_bounds__(512, 1) void lstm_rec2(
    const unsigned short* __restrict__ WT,   // [2][1024][512] bf16 (h-part = k 256..511)
    const unsigned short* __restrict__ Gx,   // [2][64][512][1024] bf16
    const float* __restrict__ ci_f, const float* __restrict__ hi_f,
    const float* __restrict__ ci_b, const float* __restrict__ hi_b,
    const int* __restrict__ length,
    float* __restrict__ hfinal)              // [2][64][256] f32
{
  __shared__ unsigned char hlds[2][8192];    // [16 b][256 dim] bf16, swizzled
  const int d = blockIdx.x >> 2, q = blockIdx.x & 3;
  const int tid = threadIdx.x, lane = tid & 63, wv = tid >> 6;
  const int lhi = lane >> 4, llo = lane & 15;
  const float* cini = d ? ci_b : ci_f;
  const float* hini = d ? hi_b : hi_f;

  // W_h fragments: wf[tc][kf], tc = gate*2 + half; col gc = gate*256 + wv*32 + half*16 + llo
  bf16x8 wf[8][8];
  #pragma unroll
  for (int tc = 0; tc < 8; ++tc) {
    const int gc = (tc >> 1) * 256 + wv * 32 + (tc & 1) * 16 + llo;
    #pragma unroll
    for (int kf = 0; kf < 8; ++kf) {
      const unsigned short* p =
          WT + ((size_t)(d * 1024 + gc)) * 512 + 256 + kf * 32 + lhi * 8;
      wf[tc][kf] = *reinterpret_cast<const bf16x8*>(p);
      asm volatile("" : "+v"(wf[tc][kf]));   // pin: no in-loop remat
    }
  }

  // state: lane owns dims {wv*32+half*16+llo} x batches {q*16+lhi*4+j}
  float c[2][4], h[2][4];
  int Ld[4];
  #pragma unroll
  for (int j = 0; j < 4; ++j) Ld[j] = length[q * 16 + lhi * 4 + j];
  #pragma unroll
  for (int hf = 0; hf < 2; ++hf) {
    const int dim = wv * 32 + hf * 16 + llo;
    #pragma unroll
    for (int j = 0; j < 4; ++j) { c[hf][j] = cini[dim]; h[hf][j] = hini[dim]; }
  }

  // h^0 -> LDS buf0
  #pragma unroll
  for (int hf = 0; hf < 2; ++hf) {
    const int dim = wv * 32 + hf * 16 + llo;
    #pragma unroll
    for (int j = 0; j < 4; ++j) {
      const int row = lhi * 4 + j;
      const int byte = (row * 512 + dim * 2) ^ ((row & 7) << 4);
      *reinterpret_cast<unsigned short*>(&hlds[0][byte]) = f2bf(h[hf][j]);
    }
  }
  __syncthreads();

  // Gx walking pointers (per batch j), plus per-tc column offsets
  const unsigned short* gxb[4];
  #pragma unroll
  for (int j = 0; j < 4; ++j)
    gxb[j] = Gx + ((size_t)(d * 64 + q * 16 + lhi * 4 + j)) * 512 * 1024 + wv * 32 + llo;

  // preload Gx[t=0]
  unsigned short gxp[8][4];
  #pragma unroll
  for (int tc = 0; tc < 8; ++tc) {
    const int off = (tc >> 1) * 256 + (tc & 1) * 16;
    #pragma unroll
    for (int j = 0; j < 4; ++j) gxp[tc][j] = gxb[j][off];
  }

  int cur = 0;
  #pragma unroll 1
  for (int t = 0; t < T_STEPS; ++t) {
    // acc init from prefetched Gx (bf16 bits -> f32)
    f32x4 acc[8];
    #pragma unroll
    for (int tc = 0; tc < 8; ++tc)
      #pragma unroll
      for (int j = 0; j < 4; ++j) acc[tc][j] = bf2f(gxp[tc][j]);

    // prefetch Gx[t+1] (latency hidden under MFMA + sync)
    if (t + 1 < T_STEPS) {
      #pragma unroll
      for (int tc = 0; tc < 8; ++tc) {
        const int off = (tc >> 1) * 256 + (tc & 1) * 16 + 1024;
        #pragma unroll
        for (int j = 0; j < 4; ++j) gxp[tc][j] = gxb[j][off];
      }
    }
    #pragma unroll
    for (int j = 0; j < 4; ++j) gxb[j] += 1024;

    // h^t from LDS (conflict-free via XOR swizzle) + 64 MFMAs
    bf16x8 ha[8];
    #pragma unroll
    for (int kf = 0; kf < 8; ++kf) {
      const int byte = (llo * 512 + (kf * 32 + lhi * 8) * 2) ^ ((llo & 7) << 4);
      ha[kf] = *reinterpret_cast<const bf16x8*>(&hlds[cur][byte]);
    }
    #pragma unroll
    for (int kf = 0; kf < 8; ++kf)
      #pragma unroll
      for (int tc = 0; tc < 8; ++tc)
        acc[tc] = __builtin_amdgcn_mfma_f32_16x16x32_bf16(ha[kf], wf[tc][kf], acc[tc], 0, 0, 0);

    // epilogue (gate order i,g,f,o) + write h^{t+1} to the other LDS buffer
    #pragma unroll
    for (int hf = 0; hf < 2; ++hf) {
      const int dim = wv * 32 + hf * 16 + llo;
      #pragma unroll
      for (int j = 0; j < 4; ++j) {
        const float gi = acc[0 + hf][j], gg = acc[2 + hf][j];
        const float gf = acc[4 + hf][j], go = acc[6 + hf][j];
        const float cn = sigm(gf) * c[hf][j] + sigm(gi) * tanh_(gg);
        const float hn = tanh_(cn) * sigm(go);
        if (t < Ld[j]) { c[hf][j] = cn; h[hf][j] = hn; }   // freeze at t >= length
        const int row = lhi * 4 + j;
        const int byte = (row * 512 + dim * 2) ^ ((row & 7) << 4);
        *reinterpret_cast<unsigned short*>(&hlds[cur ^ 1][byte]) = f2bf(h[hf][j]);
      }
    }
    __syncthreads();
    cur ^= 1;
  }

  #pragma unroll
  for (int hf = 0; hf < 2; ++hf) {
    const int dim = wv * 32 + hf * 16 + llo;
    #pragma unroll
    for (int j = 0; j < 4; ++j)
      hfinal[((size_t)(d * 64 + q * 16 + lhi * 4 + j)) * 256 + dim] = h[hf][j];
  }
}

// ================= FALLBACK (R4-identical) for small ws_size =================
__global__ void prep_x(const float* __restrict__ x, unsigned short* __restrict__ xbf) {
  size_t i = ((size_t)blockIdx.x * 256 + threadIdx.x) * 4;
  const float4 v = *reinterpret_cast<const float4*>(x + i);
  uint2 o;
  o.x = (unsigned)f2bf(v.x) | ((unsigned)f2bf(v.y) << 16);
  o.y = (unsigned)f2bf(v.z) | ((unsigned)f2bf(v.w) << 16);
  *reinterpret_cast<uint2*>(xbf + i) = o;
}

__global__ __launch_bounds__(256, 1) void lstm_rec_fb(
    const unsigned short* __restrict__ xbf, const unsigned short* __restrict__ WT,
    const float* __restrict__ bias_f, const float* __restrict__ bias_b,
    const float* __restrict__ ci_f, const float* __restrict__ hi_f,
    const float* __restrict__ ci_b, const float* __restrict__ hi_b,
    const int* __restrict__ length,
    unsigned int* hbuf, float* hfinal)
{
  const int blk = blockIdx.x;
  const int d = blk >> 4, g = blk & 15;
  const int lane = threadIdx.x & 63;
  const int wv = threadIdx.x >> 6;
  const int lhi = lane >> 4, llo = lane & 15;
  const float* bias = d ? bias_b : bias_f;
  const float* cini = d ? ci_b : ci_f;
  const float* hini = d ? hi_b : hi_f;
  unsigned int* hb = hbuf + (size_t)d * (2 * BATCH * DIMS);
  const int dim = g * 16 + llo;

  bf16x8 wf[4][16];
  #pragma unroll
  for (int gate = 0; gate < 4; ++gate)
    #pragma unroll
    for (int ks = 0; ks < 16; ++ks) {
      const unsigned short* p =
          WT + ((size_t)(d * 1024 + gate * 256 + dim)) * 512 + ks * 32 + lhi * 8;
      wf[gate][ks] = *reinterpret_cast<const bf16x8*>(p);
      asm volatile("" : "+v"(wf[gate][ks]));
    }
  float bs[4];
  #pragma unroll
  for (int gate = 0; gate < 4; ++gate) bs[gate] = bias[gate * 256 + dim];

  const int b0 = wv * 16 + lhi * 4;
  float c[4], h[4]; int Ld[4];
  #pragma unroll
  for (int j = 0; j < 4; ++j) { c[j] = cini[dim]; h[j] = hini[dim]; Ld[j] = length[b0 + j]; }
  const int bx = wv * 16 + llo;
  const int Lx = length[bx];

  #pragma unroll
  for (int j = 0; j < 4; ++j) {
    unsigned int val = (1u << 16) | (unsigned int)f2bf(h[j]);
    const unsigned int* ap = hb + (b0 + j) * DIMS + dim;
    asm volatile("global_store_dword %0, %1, off sc0 sc1" :: "v"(ap), "v"(val) : "memory");
  }

  bf16x8 xa[8];
  {
    const int tx0 = (d == 0) ? 0 : (Lx - 1);
    const unsigned short* xp = xbf + ((size_t)bx * T_STEPS + tx0) * DIMS + lhi * 8;
    #pragma unroll
    for (int ks = 0; ks < 8; ++ks) xa[ks] = *reinterpret_cast<const bf16x8*>(xp + ks * 32);
  }

  #pragma unroll 1
  for (int t = 0; t < T_STEPS; ++t) {
    f32x4 acc[4];
    #pragma unroll
    for (int gate = 0; gate < 4; ++gate) acc[gate] = bcast4(bs[gate]);
    #pragma unroll
    for (int ks = 0; ks < 8; ++ks)
      #pragma unroll
      for (int gate = 0; gate < 4; ++gate)
        acc[gate] = __builtin_amdgcn_mfma_f32_16x16x32_bf16(xa[ks], wf[gate][ks], acc[gate], 0, 0, 0);

    const unsigned int* hr = hb + (size_t)(t & 1) * (BATCH * DIMS) + bx * DIMS + lhi * 8;
    u32x4 w[16];
    {
      const unsigned int tagsh = (unsigned int)(t + 1) << 16;
      bool ready; unsigned int spins = 0;
      do {
        #pragma unroll
        for (int ks = 0; ks < 8; ++ks) {
          const unsigned int* p = hr + ks * 32;
          asm volatile("global_load_dwordx4 %0, %1, off sc0 sc1" : "=v"(w[2*ks]) : "v"(p) : "memory");
          asm volatile("global_load_dwordx4 %0, %1, off sc0 sc1" : "=v"(w[2*ks+1]) : "v"(p + 4) : "memory");
        }
        asm volatile("s_waitcnt vmcnt(0)" ::: "memory");
        unsigned int bad = 0;
        #pragma unroll
        for (int i = 0; i < 16; ++i)
          #pragma unroll
          for (int qq = 0; qq < 4; ++qq) bad |= (w[i][qq] ^ tagsh);
        ready = ((bad >> 16) == 0);
        if (++spins > (1u << 20)) ready = true;
      } while (!__all(ready));
    }
    __builtin_amdgcn_sched_barrier(0);

    bf16x8 ha[8];
    #pragma unroll
    for (int ks = 0; ks < 8; ++ks) {
      union { bf16x8 v; unsigned int dd[4]; } u;
      u.dd[0] = (w[2*ks][0]   & 0xFFFFu) | (w[2*ks][1]   << 16);
      u.dd[1] = (w[2*ks][2]   & 0xFFFFu) | (w[2*ks][3]   << 16);
      u.dd[2] = (w[2*ks+1][0] & 0xFFFFu) | (w[2*ks+1][1] << 16);
      u.dd[3] = (w[2*ks+1][2] & 0xFFFFu) | (w[2*ks+1][3] << 16);
      ha[ks] = u.v;
    }
    if (t + 1 < T_STEPS) {
      const int tn = t + 1;
      const int tx = (d == 0) ? tn : ((tn < Lx) ? (Lx - 1 - tn) : tn);
      const unsigned short* xp = xbf + ((size_t)bx * T_STEPS + tx) * DIMS + lhi * 8;
      #pragma unroll
      for (int ks = 0; ks < 8; ++ks) xa[ks] = *reinterpret_cast<const bf16x8*>(xp + ks * 32);
    }
    #pragma unroll
    for (int ks = 0; ks < 8; ++ks)
      #pragma unroll
      for (int gate = 0; gate < 4; ++gate)
        acc[gate] = __builtin_amdgcn_mfma_f32_16x16x32_bf16(ha[ks], wf[gate][ks + 8], acc[gate], 0, 0, 0);

    unsigned int* hw = hb + (size_t)((t + 1) & 1) * (BATCH * DIMS);
    const unsigned int ptag = (unsigned int)(t + 2) << 16;
    #pragma unroll
    for (int j = 0; j < 4; ++j) {
      const float gi = acc[0][j], gg = acc[1][j], gf = acc[2][j], go = acc[3][j];
      const float cn = sigm(gf) * c[j] + sigm(gi) * tanh_(gg);
      const float hn = tanh_(cn) * sigm(go);
      if (t < Ld[j]) { c[j] = cn; h[j] = hn; }
      unsigned int val = ptag | (unsigned int)f2bf(h[j]);
      const unsigned int* ap = hw + (b0 + j) * DIMS + dim;
      asm volatile("global_store_dword %0, %1, off sc0 sc1" :: "v"(ap), "v"(val) : "memory");
    }
  }
  #pragma unroll
  for (int j = 0; j < 4; ++j)
    hfinal[((size_t)d * BATCH + b0 + j) * DIMS + dim] = h[j];
}

// ---- out[64,256] = concat(h_f, h_b) @ W_fc[512,256], f32 ----
__global__ void final_gemm(const float* __restrict__ hfinal, const float* __restrict__ Wfc,
                           float* __restrict__ out) {
  __shared__ float hrow[512];
  const int b = blockIdx.x, col = threadIdx.x;
  hrow[col]       = hfinal[(size_t)b * DIMS + col];
  hrow[256 + col] = hfinal[(size_t)(BATCH + b) * DIMS + col];
  __syncthreads();
  float acc = 0.f;
  #pragma unroll 8
  for (int k = 0; k < 512; ++k) acc = fmaf(hrow[k], Wfc[(size_t)k * DIMS + col], acc);
  out[(size_t)b * DIMS + col] = acc;
}

extern "C" void kernel_launch(void* const* d_in, const int* in_sizes, int n_in,
                              void* d_out, int out_size, void* d_ws, size_t ws_size,
                              hipStream_t stream) {
  const float* x        = (const float*)d_in[0];
  const int*   length   = (const int*)d_in[1];
  const float* W_f      = (const float*)d_in[2];
  const float* b_f      = (const float*)d_in[3];
  const float* W_b      = (const float*)d_in[4];
  const float* b_b      = (const float*)d_in[5];
  const float* c_init_f = (const float*)d_in[6];
  const float* h_init_f = (const float*)d_in[7];
  const float* c_init_b = (const float*)d_in[8];
  const float* h_init_b = (const float*)d_in[9];
  const float* W_fc     = (const float*)d_in[10];
  float* out = (float*)d_out;
  char* ws = (char*)d_ws;

  const size_t WT_SZ = 2097152;            // [2][1024][512] bf16
  const size_t GX_SZ = 134217728;          // [2][64][512][1024] bf16
  const size_t HF_SZ = 131072;             // [2][64][256] f32
  const size_t FAST_NEED = WT_SZ + GX_SZ + HF_SZ;

  if (ws_size >= FAST_NEED) {
    unsigned short* WT  = (unsigned short*)(ws);
    unsigned short* Gx  = (unsigned short*)(ws + WT_SZ);
    float* hfinal       = (float*)(ws + WT_SZ + GX_SZ);

    prep_w<<<2048, 512, 0, stream>>>(W_f, W_b, WT);
    gx_gemm<<<4096, 512, 0, stream>>>(x, length, WT, b_f, b_b, Gx);
    lstm_rec2<<<8, 512, 0, stream>>>(WT, Gx, c_init_f, h_init_f, c_init_b, h_init_b,
                                     length, hfinal);
    final_gemm<<<BATCH, 256, 0, stream>>>(hfinal, W_fc, out);
  } else {
    unsigned short* xbf = (unsigned short*)(ws);                       // 16 MB
    unsigned short* WT  = (unsigned short*)(ws + 16777216);            //  2 MB
    unsigned int*   hbf = (unsigned int*)(ws + 16777216 + 2097152);    // 512 KB
    float* hfinal       = (float*)(ws + 16777216 + 2097152 + 524288);  // 128 KB

    hipMemsetAsync(hbf, 0, NDIR * 2 * BATCH * DIMS * sizeof(unsigned int), stream);
    prep_x<<<8192, 256, 0, stream>>>(x, xbf);
    prep_w<<<2048, 512, 0, stream>>>(W_f, W_b, WT);
    lstm_rec_fb<<<32, 256, 0, stream>>>(xbf, WT, b_f, b_b,
                                        c_init_f, h_init_f, c_init_b, h_init_b,
                                        length, hbf, hfinal);
    final_gemm<<<BATCH, 256, 0, stream>>>(hfinal, W_fc, out);
  }
}

// Round 10
// 3114.758 us; speedup vs baseline: 1.5392x; 1.5392x over previous
//
#include <hip/hip_runtime.h>

#define T_STEPS 512
#define BATCH   64
#define DIMS    256
#define NDIR    2

typedef short bf16x8 __attribute__((ext_vector_type(8)));
typedef float f32x4  __attribute__((ext_vector_type(4)));
typedef unsigned int u32x4 __attribute__((ext_vector_type(4)));

__device__ __forceinline__ unsigned short f2bf(float f) {
  union { float f; unsigned int u; } v; v.f = f;
  unsigned int b = v.u;
  return (unsigned short)((b + 0x7FFFu + ((b >> 16) & 1u)) >> 16);
}
__device__ __forceinline__ float bf2f(unsigned short s) {
  union { unsigned int u; float f; } v; v.u = ((unsigned int)s) << 16; return v.f;
}
__device__ __forceinline__ float sigm(float x) {
  return __builtin_amdgcn_rcpf(1.0f + __builtin_amdgcn_exp2f(-1.44269504f * x));
}
__device__ __forceinline__ float tanh_(float x) {
  return 1.0f - 2.0f * __builtin_amdgcn_rcpf(1.0f + __builtin_amdgcn_exp2f(2.88539008f * x));
}
__device__ __forceinline__ f32x4 bcast4(float s) {
  f32x4 v; v[0] = s; v[1] = s; v[2] = s; v[3] = s; return v;
}

// ---- prep: W [512][1024] f32 -> WT [2][1024 cols][512 k] bf16 (transposed) ----
__global__ void prep_w(const float* __restrict__ Wf, const float* __restrict__ Wb,
                       unsigned short* __restrict__ WT) {
  int d = blockIdx.x >> 10, col = blockIdx.x & 1023;
  const float* W = d ? Wb : Wf;
  int k = threadIdx.x;
  WT[((size_t)(d * 1024 + col)) * 512 + k] = f2bf(W[(size_t)k * 1024 + col]);
}

// ---- Gx = x_dir @ W_x + bias -> bf16 [2][64 b][512 t][256 dim][4 gate] ----
// Gate-interleaved so the recurrence reads one 8B word per (batch, dim).
// Block = d x mt(128 (b,t) rows) x dc(32-dim chunk, all 4 gates = 128 N-cols).
__global__ __launch_bounds__(512, 1) void gx_gemm(
    const float* __restrict__ x, const int* __restrict__ length,
    const unsigned short* __restrict__ WT,
    const float* __restrict__ bias_f, const float* __restrict__ bias_b,
    unsigned short* __restrict__ Gx)
{
  __shared__ unsigned char Alds[65536];   // [128 rows][256 k] bf16, swizzled
  const int bid = blockIdx.x;
  const int d = bid >> 11, mt = (bid >> 3) & 255, dc = bid & 7;
  const int tid = threadIdx.x;
  const float* bias = d ? bias_b : bias_f;

  // stage A rows (b,t) -> LDS bf16 (proven in R9)
  {
    const int r = tid >> 2, q = tid & 3;
    const int m = mt * 128 + r;
    const int b = m >> 9, t = m & 511;
    const int L = length[b];
    const int tx = (d == 0) ? t : ((t < L) ? (L - 1 - t) : t);
    const float* xp = x + ((size_t)b * 512 + tx) * 256 + q * 64;
    #pragma unroll
    for (int i = 0; i < 8; ++i) {
      const float4 v0 = *reinterpret_cast<const float4*>(xp + i * 8);
      const float4 v1 = *reinterpret_cast<const float4*>(xp + i * 8 + 4);
      union { bf16x8 v; unsigned short s[8]; } u;
      u.s[0] = f2bf(v0.x); u.s[1] = f2bf(v0.y); u.s[2] = f2bf(v0.z); u.s[3] = f2bf(v0.w);
      u.s[4] = f2bf(v1.x); u.s[5] = f2bf(v1.y); u.s[6] = f2bf(v1.z); u.s[7] = f2bf(v1.w);
      const int byte = (r * 512 + (q * 64 + i * 8) * 2) ^ ((r & 7) << 4);
      *reinterpret_cast<bf16x8*>(&Alds[byte]) = u.v;
    }
  }
  __syncthreads();

  const int lane = tid & 63, wv = tid >> 6;      // 8 waves x 16 M-rows
  const int lhi = lane >> 4, llo = lane & 15;

  // tc = gate*2 + sub ; gc = gate*256 + dc*32 + sub*16 + llo
  f32x4 acc[8];
  #pragma unroll
  for (int tc = 0; tc < 8; ++tc) {
    const int gc = (tc >> 1) * 256 + dc * 32 + (tc & 1) * 16 + llo;
    acc[tc] = bcast4(bias[gc]);
  }

  #pragma unroll
  for (int kf = 0; kf < 8; ++kf) {
    const int row = 16 * wv + llo;
    const int abyte = (row * 512 + (kf * 32 + lhi * 8) * 2) ^ ((row & 7) << 4);
    const bf16x8 af = *reinterpret_cast<const bf16x8*>(&Alds[abyte]);
    #pragma unroll
    for (int tc = 0; tc < 8; ++tc) {
      const int gc = (tc >> 1) * 256 + dc * 32 + (tc & 1) * 16 + llo;
      const unsigned short* bp =
          WT + ((size_t)(d * 1024 + gc)) * 512 + kf * 32 + lhi * 8;
      const bf16x8 bf = *reinterpret_cast<const bf16x8*>(bp);
      acc[tc] = __builtin_amdgcn_mfma_f32_16x16x32_bf16(af, bf, acc[tc], 0, 0, 0);
    }
  }

  // epilogue: pack 4 gates (i,g,f,o) per (sub,j) -> one 8B store
  #pragma unroll
  for (int sub = 0; sub < 2; ++sub) {
    const int dim = dc * 32 + sub * 16 + llo;
    #pragma unroll
    for (int j = 0; j < 4; ++j) {
      const int m = mt * 128 + 16 * wv + lhi * 4 + j;
      const int b = m >> 9, t = m & 511;
      uint2 o;
      o.x = (unsigned)f2bf(acc[0 * 2 + sub][j]) | ((unsigned)f2bf(acc[1 * 2 + sub][j]) << 16);
      o.y = (unsigned)f2bf(acc[2 * 2 + sub][j]) | ((unsigned)f2bf(acc[3 * 2 + sub][j]) << 16);
      const size_t idx = ((((size_t)d * 64 + b) * 512 + t) * 256 + dim) * 4;
      *reinterpret_cast<uint2*>(Gx + idx) = o;
    }
  }
}

// ---- recurrence: 16 blocks (8/dir), W_h register-resident, R4 protocol ----
// Block g owns dims [g*32, g*32+32) x 4 gates (128 gate-cols). Gates =
// Gx[t] (prefetched 8B/dim-pair) + h @ W_h. h exchange: flag-in-data
// (tag<<16|bf16) sc0 sc1 stores + dwordx4 poll with vmcnt(0) — R4 verbatim.
__global__ __launch_bounds__(256, 1) void lstm_rec3(
    const unsigned short* __restrict__ WT,   // [2][1024][512] bf16 (h-part k=256..511)
    const unsigned short* __restrict__ Gx,   // [2][64][512][256][4] bf16
    const float* __restrict__ ci_f, const float* __restrict__ hi_f,
    const float* __restrict__ ci_b, const float* __restrict__ hi_b,
    const int* __restrict__ length,
    unsigned int* hbuf,     // [2 dir][2 slot][64][256] u32 (tag<<16 | bf16 h)
    float* __restrict__ hfinal)              // [2][64][256] f32
{
  const int blk = blockIdx.x;
  const int d = blk >> 3, g = blk & 7;
  const int lane = threadIdx.x & 63;
  const int wv = threadIdx.x >> 6;
  const int lhi = lane >> 4, llo = lane & 15;

  const float* cini = d ? ci_b : ci_f;
  const float* hini = d ? hi_b : hi_f;
  unsigned int* hb = hbuf + (size_t)d * (2 * BATCH * DIMS);

  // W_h fragments: wf[tc][kf], tc = gate*2+sub; col = gate*256 + g*32 + sub*16 + llo
  bf16x8 wf[8][8];
  #pragma unroll
  for (int tc = 0; tc < 8; ++tc) {
    const int col = (tc >> 1) * 256 + g * 32 + (tc & 1) * 16 + llo;
    #pragma unroll
    for (int kf = 0; kf < 8; ++kf) {
      const unsigned short* p =
          WT + ((size_t)(d * 1024 + col)) * 512 + 256 + kf * 32 + lhi * 8;
      wf[tc][kf] = *reinterpret_cast<const bf16x8*>(p);
      asm volatile("" : "+v"(wf[tc][kf]));   // pin: no in-loop remat
    }
  }

  // state: lane owns dims {g*32+sub*16+llo} x batches {wv*16+lhi*4+j}
  const int b0 = wv * 16 + lhi * 4;
  float c[2][4], h[2][4];
  int Ld[4];
  #pragma unroll
  for (int j = 0; j < 4; ++j) Ld[j] = length[b0 + j];
  #pragma unroll
  for (int s = 0; s < 2; ++s) {
    const int dim = g * 32 + s * 16 + llo;
    #pragma unroll
    for (int j = 0; j < 4; ++j) { c[s][j] = cini[dim]; h[s][j] = hini[dim]; }
  }

  // A layout: row(batch) = wv*16 + llo, k = kf*32 + lhi*8 + e
  const int bx = wv * 16 + llo;

  // publish h^0 (tag=1) into slot 0
  #pragma unroll
  for (int s = 0; s < 2; ++s) {
    const int dim = g * 32 + s * 16 + llo;
    #pragma unroll
    for (int j = 0; j < 4; ++j) {
      unsigned int val = (1u << 16) | (unsigned int)f2bf(h[s][j]);
      const unsigned int* ap = hb + (b0 + j) * DIMS + dim;
      asm volatile("global_store_dword %0, %1, off sc0 sc1"
                   :: "v"(ap), "v"(val) : "memory");
    }
  }

  // Gx prefetch for t=0: per (j, sub) one 8B word (4 gates)
  uint2 gxp[4][2];
  #pragma unroll
  for (int j = 0; j < 4; ++j)
    #pragma unroll
    for (int s = 0; s < 2; ++s) {
      const int dim = g * 32 + s * 16 + llo;
      const size_t idx = ((((size_t)d * 64 + b0 + j) * 512 + 0) * 256 + dim) * 4;
      gxp[j][s] = *reinterpret_cast<const uint2*>(Gx + idx);
    }

  #pragma unroll 1
  for (int t = 0; t < T_STEPS; ++t) {
    // acc init from prefetched Gx: acc[gate*2+sub][j]
    f32x4 acc[8];
    #pragma unroll
    for (int j = 0; j < 4; ++j)
      #pragma unroll
      for (int s = 0; s < 2; ++s) {
        const unsigned int w0 = gxp[j][s].x, w1 = gxp[j][s].y;
        acc[0 + s][j] = bf2f((unsigned short)(w0 & 0xFFFFu));
        acc[2 + s][j] = bf2f((unsigned short)(w0 >> 16));
        acc[4 + s][j] = bf2f((unsigned short)(w1 & 0xFFFFu));
        acc[6 + s][j] = bf2f((unsigned short)(w1 >> 16));
      }

    // poll own k-slice of h^t until all 64 words carry tag t+1 (R4 verbatim)
    const unsigned int* hr = hb + (size_t)(t & 1) * (BATCH * DIMS) + bx * DIMS + lhi * 8;
    u32x4 w[16];
    {
      const unsigned int tagsh = (unsigned int)(t + 1) << 16;
      bool ready;
      unsigned int spins = 0;
      do {
        #pragma unroll
        for (int ks = 0; ks < 8; ++ks) {
          const unsigned int* p = hr + ks * 32;
          asm volatile("global_load_dwordx4 %0, %1, off sc0 sc1"
                       : "=v"(w[2 * ks]) : "v"(p) : "memory");
          asm volatile("global_load_dwordx4 %0, %1, off sc0 sc1"
                       : "=v"(w[2 * ks + 1]) : "v"(p + 4) : "memory");
        }
        asm volatile("s_waitcnt vmcnt(0)" ::: "memory");
        unsigned int bad = 0;
        #pragma unroll
        for (int i = 0; i < 16; ++i)
          #pragma unroll
          for (int q = 0; q < 4; ++q)
            bad |= (w[i][q] ^ tagsh);
        ready = ((bad >> 16) == 0);
        if (++spins > (1u << 20)) ready = true;   // escape -> visible fail
      } while (!__all(ready));
    }
    __builtin_amdgcn_sched_barrier(0);

    // repack low halves -> bf16x8 A-fragments
    bf16x8 ha[8];
    #pragma unroll
    for (int ks = 0; ks < 8; ++ks) {
      union { bf16x8 v; unsigned int dd[4]; } u;
      u.dd[0] = (w[2 * ks][0]     & 0xFFFFu) | (w[2 * ks][1]     << 16);
      u.dd[1] = (w[2 * ks][2]     & 0xFFFFu) | (w[2 * ks][3]     << 16);
      u.dd[2] = (w[2 * ks + 1][0] & 0xFFFFu) | (w[2 * ks + 1][1] << 16);
      u.dd[3] = (w[2 * ks + 1][2] & 0xFFFFu) | (w[2 * ks + 1][3] << 16);
      ha[ks] = u.v;
    }

    // prefetch Gx[t+1] (cached; drained by next poll's vmcnt)
    if (t + 1 < T_STEPS) {
      #pragma unroll
      for (int j = 0; j < 4; ++j)
        #pragma unroll
        for (int s = 0; s < 2; ++s) {
          const int dim = g * 32 + s * 16 + llo;
          const size_t idx = ((((size_t)d * 64 + b0 + j) * 512 + (t + 1)) * 256 + dim) * 4;
          gxp[j][s] = *reinterpret_cast<const uint2*>(Gx + idx);
        }
    }

    // h-part MFMAs: 64 per wave
    #pragma unroll
    for (int kf = 0; kf < 8; ++kf)
      #pragma unroll
      for (int tc = 0; tc < 8; ++tc)
        acc[tc] = __builtin_amdgcn_mfma_f32_16x16x32_bf16(ha[kf], wf[tc][kf], acc[tc], 0, 0, 0);

    // epilogue (gate order i,g,f,o) + publish h^{t+1} (tag t+2)
    unsigned int* hw = hb + (size_t)((t + 1) & 1) * (BATCH * DIMS);
    const unsigned int ptag = (unsigned int)(t + 2) << 16;
    #pragma unroll
    for (int s = 0; s < 2; ++s) {
      const int dim = g * 32 + s * 16 + llo;
      #pragma unroll
      for (int j = 0; j < 4; ++j) {
        const float gi = acc[0 + s][j], gg = acc[2 + s][j];
        const float gf = acc[4 + s][j], go = acc[6 + s][j];
        const float cn = sigm(gf) * c[s][j] + sigm(gi) * tanh_(gg);
        const float hn = tanh_(cn) * sigm(go);
        if (t < Ld[j]) { c[s][j] = cn; h[s][j] = hn; }   // freeze at t >= length
        unsigned int val = ptag | (unsigned int)f2bf(h[s][j]);
        const unsigned int* ap = hw + (b0 + j) * DIMS + dim;
        asm volatile("global_store_dword %0, %1, off sc0 sc1"
                     :: "v"(ap), "v"(val) : "memory");
      }
    }
  }

  // final frozen h in f32
  #pragma unroll
  for (int s = 0; s < 2; ++s) {
    const int dim = g * 32 + s * 16 + llo;
    #pragma unroll
    for (int j = 0; j < 4; ++j)
      hfinal[((size_t)(d * 64 + b0 + j)) * 256 + dim] = h[s][j];
  }
}

// ================= FALLBACK (R4-identical) for small ws_size =================
__global__ void prep_x(const float* __restrict__ x, unsigned short* __restrict__ xbf) {
  size_t i = ((size_t)blockIdx.x * 256 + threadIdx.x) * 4;
  const float4 v = *reinterpret_cast<const float4*>(x + i);
  uint2 o;
  o.x = (unsigned)f2bf(v.x) | ((unsigned)f2bf(v.y) << 16);
  o.y = (unsigned)f2bf(v.z) | ((unsigned)f2bf(v.w) << 16);
  *reinterpret_cast<uint2*>(xbf + i) = o;
}

__global__ __launch_bounds__(256, 1) void lstm_rec_fb(
    const unsigned short* __restrict__ xbf, const unsigned short* __restrict__ WT,
    const float* __restrict__ bias_f, const float* __restrict__ bias_b,
    const float* __restrict__ ci_f, const float* __restrict__ hi_f,
    const float* __restrict__ ci_b, const float* __restrict__ hi_b,
    const int* __restrict__ length,
    unsigned int* hbuf, float* hfinal)
{
  const int blk = blockIdx.x;
  const int d = blk >> 4, g = blk & 15;
  const int lane = threadIdx.x & 63;
  const int wv = threadIdx.x >> 6;
  const int lhi = lane >> 4, llo = lane & 15;
  const float* bias = d ? bias_b : bias_f;
  const float* cini = d ? ci_b : ci_f;
  const float* hini = d ? hi_b : hi_f;
  unsigned int* hb = hbuf + (size_t)d * (2 * BATCH * DIMS);
  const int dim = g * 16 + llo;

  bf16x8 wf[4][16];
  #pragma unroll
  for (int gate = 0; gate < 4; ++gate)
    #pragma unroll
    for (int ks = 0; ks < 16; ++ks) {
      const unsigned short* p =
          WT + ((size_t)(d * 1024 + gate * 256 + dim)) * 512 + ks * 32 + lhi * 8;
      wf[gate][ks] = *reinterpret_cast<const bf16x8*>(p);
      asm volatile("" : "+v"(wf[gate][ks]));
    }
  float bs[4];
  #pragma unroll
  for (int gate = 0; gate < 4; ++gate) bs[gate] = bias[gate * 256 + dim];

  const int b0 = wv * 16 + lhi * 4;
  float c[4], h[4]; int Ld[4];
  #pragma unroll
  for (int j = 0; j < 4; ++j) { c[j] = cini[dim]; h[j] = hini[dim]; Ld[j] = length[b0 + j]; }
  const int bx = wv * 16 + llo;
  const int Lx = length[bx];

  #pragma unroll
  for (int j = 0; j < 4; ++j) {
    unsigned int val = (1u << 16) | (unsigned int)f2bf(h[j]);
    const unsigned int* ap = hb + (b0 + j) * DIMS + dim;
    asm volatile("global_store_dword %0, %1, off sc0 sc1" :: "v"(ap), "v"(val) : "memory");
  }

  bf16x8 xa[8];
  {
    const int tx0 = (d == 0) ? 0 : (Lx - 1);
    const unsigned short* xp = xbf + ((size_t)bx * T_STEPS + tx0) * DIMS + lhi * 8;
    #pragma unroll
    for (int ks = 0; ks < 8; ++ks) xa[ks] = *reinterpret_cast<const bf16x8*>(xp + ks * 32);
  }

  #pragma unroll 1
  for (int t = 0; t < T_STEPS; ++t) {
    f32x4 acc[4];
    #pragma unroll
    for (int gate = 0; gate < 4; ++gate) acc[gate] = bcast4(bs[gate]);
    #pragma unroll
    for (int ks = 0; ks < 8; ++ks)
      #pragma unroll
      for (int gate = 0; gate < 4; ++gate)
        acc[gate] = __builtin_amdgcn_mfma_f32_16x16x32_bf16(xa[ks], wf[gate][ks], acc[gate], 0, 0, 0);

    const unsigned int* hr = hb + (size_t)(t & 1) * (BATCH * DIMS) + bx * DIMS + lhi * 8;
    u32x4 w[16];
    {
      const unsigned int tagsh = (unsigned int)(t + 1) << 16;
      bool ready; unsigned int spins = 0;
      do {
        #pragma unroll
        for (int ks = 0; ks < 8; ++ks) {
          const unsigned int* p = hr + ks * 32;
          asm volatile("global_load_dwordx4 %0, %1, off sc0 sc1" : "=v"(w[2*ks]) : "v"(p) : "memory");
          asm volatile("global_load_dwordx4 %0, %1, off sc0 sc1" : "=v"(w[2*ks+1]) : "v"(p + 4) : "memory");
        }
        asm volatile("s_waitcnt vmcnt(0)" ::: "memory");
        unsigned int bad = 0;
        #pragma unroll
        for (int i = 0; i < 16; ++i)
          #pragma unroll
          for (int qq = 0; qq < 4; ++qq) bad |= (w[i][qq] ^ tagsh);
        ready = ((bad >> 16) == 0);
        if (++spins > (1u << 20)) ready = true;
      } while (!__all(ready));
    }
    __builtin_amdgcn_sched_barrier(0);

    bf16x8 ha[8];
    #pragma unroll
    for (int ks = 0; ks < 8; ++ks) {
      union { bf16x8 v; unsigned int dd[4]; } u;
      u.dd[0] = (w[2*ks][0]   & 0xFFFFu) | (w[2*ks][1]   << 16);
      u.dd[1] = (w[2*ks][2]   & 0xFFFFu) | (w[2*ks][3]   << 16);
      u.dd[2] = (w[2*ks+1][0] & 0xFFFFu) | (w[2*ks+1][1] << 16);
      u.dd[3] = (w[2*ks+1][2] & 0xFFFFu) | (w[2*ks+1][3] << 16);
      ha[ks] = u.v;
    }
    if (t + 1 < T_STEPS) {
      const int tn = t + 1;
      const int tx = (d == 0) ? tn : ((tn < Lx) ? (Lx - 1 - tn) : tn);
      const unsigned short* xp = xbf + ((size_t)bx * T_STEPS + tx) * DIMS + lhi * 8;
      #pragma unroll
      for (int ks = 0; ks < 8; ++ks) xa[ks] = *reinterpret_cast<const bf16x8*>(xp + ks * 32);
    }
    #pragma unroll
    for (int ks = 0; ks < 8; ++ks)
      #pragma unroll
      for (int gate = 0; gate < 4; ++gate)
        acc[gate] = __builtin_amdgcn_mfma_f32_16x16x32_bf16(ha[ks], wf[gate][ks + 8], acc[gate], 0, 0, 0);

    unsigned int* hw = hb + (size_t)((t + 1) & 1) * (BATCH * DIMS);
    const unsigned int ptag = (unsigned int)(t + 2) << 16;
    #pragma unroll
    for (int j = 0; j < 4; ++j) {
      const float gi = acc[0][j], gg = acc[1][j], gf = acc[2][j], go = acc[3][j];
      const float cn = sigm(gf) * c[j] + sigm(gi) * tanh_(gg);
      const float hn = tanh_(cn) * sigm(go);
      if (t < Ld[j]) { c[j] = cn; h[j] = hn; }
      unsigned int val = ptag | (unsigned int)f2bf(h[j]);
      const unsigned int* ap = hw + (b0 + j) * DIMS + dim;
      asm volatile("global_store_dword %0, %1, off sc0 sc1" :: "v"(ap), "v"(val) : "memory");
    }
  }
  #pragma unroll
  for (int j = 0; j < 4; ++j)
    hfinal[((size_t)d * BATCH + b0 + j) * DIMS + dim] = h[j];
}

// ---- out[64,256] = concat(h_f, h_b) @ W_fc[512,256], f32 ----
__global__ void final_gemm(const float* __restrict__ hfinal, const float* __restrict__ Wfc,
                           float* __restrict__ out) {
  __shared__ float hrow[512];
  const int b = blockIdx.x, col = threadIdx.x;
  hrow[col]       = hfinal[(size_t)b * DIMS + col];
  hrow[256 + col] = hfinal[(size_t)(BATCH + b) * DIMS + col];
  __syncthreads();
  float acc = 0.f;
  #pragma unroll 8
  for (int k = 0; k < 512; ++k) acc = fmaf(hrow[k], Wfc[(size_t)k * DIMS + col], acc);
  out[(size_t)b * DIMS + col] = acc;
}

extern "C" void kernel_launch(void* const* d_in, const int* in_sizes, int n_in,
                              void* d_out, int out_size, void* d_ws, size_t ws_size,
                              hipStream_t stream) {
  const float* x        = (const float*)d_in[0];
  const int*   length   = (const int*)d_in[1];
  const float* W_f      = (const float*)d_in[2];
  const float* b_f      = (const float*)d_in[3];
  const float* W_b      = (const float*)d_in[4];
  const float* b_b      = (const float*)d_in[5];
  const float* c_init_f = (const float*)d_in[6];
  const float* h_init_f = (const float*)d_in[7];
  const float* c_init_b = (const float*)d_in[8];
  const float* h_init_b = (const float*)d_in[9];
  const float* W_fc     = (const float*)d_in[10];
  float* out = (float*)d_out;
  char* ws = (char*)d_ws;

  const size_t WT_SZ = 2097152;            // [2][1024][512] bf16
  const size_t GX_SZ = 134217728;          // [2][64][512][256][4] bf16
  const size_t HB_SZ = 524288;             // [2][2][64][256] u32 tags
  const size_t HF_SZ = 131072;             // [2][64][256] f32
  const size_t FAST_NEED = WT_SZ + GX_SZ + HB_SZ + HF_SZ;

  if (ws_size >= FAST_NEED) {
    unsigned short* WT  = (unsigned short*)(ws);
    unsigned short* Gx  = (unsigned short*)(ws + WT_SZ);
    unsigned int*   hbf = (unsigned int*)(ws + WT_SZ + GX_SZ);
    float* hfinal       = (float*)(ws + WT_SZ + GX_SZ + HB_SZ);

    hipMemsetAsync(hbf, 0, HB_SZ, stream);   // zero tags each call
    prep_w<<<2048, 512, 0, stream>>>(W_f, W_b, WT);
    gx_gemm<<<4096, 512, 0, stream>>>(x, length, WT, b_f, b_b, Gx);
    lstm_rec3<<<16, 256, 0, stream>>>(WT, Gx, c_init_f, h_init_f, c_init_b, h_init_b,
                                      length, hbf, hfinal);
    final_gemm<<<BATCH, 256, 0, stream>>>(hfinal, W_fc, out);
  } else {
    unsigned short* xbf = (unsigned short*)(ws);                       // 16 MB
    unsigned short* WT  = (unsigned short*)(ws + 16777216);            //  2 MB
    unsigned int*   hbf = (unsigned int*)(ws + 16777216 + 2097152);    // 512 KB
    float* hfinal       = (float*)(ws + 16777216 + 2097152 + 524288);  // 128 KB

    hipMemsetAsync(hbf, 0, NDIR * 2 * BATCH * DIMS * sizeof(unsigned int), stream);
    prep_x<<<8192, 256, 0, stream>>>(x, xbf);
    prep_w<<<2048, 512, 0, stream>>>(W_f, W_b, WT);
    lstm_rec_fb<<<32, 256, 0, stream>>>(xbf, WT, b_f, b_b,
                                        c_init_f, h_init_f, c_init_b, h_init_b,
                                        length, hbf, hfinal);
    final_gemm<<<BATCH, 256, 0, stream>>>(hfinal, W_fc, out);
  }
}